// Round 2
// baseline (327.096 us; speedup 1.0000x reference)
//
#include <hip/hip_runtime.h>

#define NN 35
#define NE 1190   // 35*34, src-major: edges of src s are e in [s*34, s*34+34)

// Incoming edge to d from s (s != d): position of d in s's dst list
__device__ __forceinline__ int in_edge(int s, int d) {
    return s * 34 + (d < s ? d : d - 1);
}

// ---------------- Layer 1 (I=1) fused: h1[d,o] directly ----------------
__global__ __launch_bounds__(512)
void layer1_kernel(const float* __restrict__ x,      // [35,1]
                   const float* __restrict__ ea,     // [1190,4]
                   const float* __restrict__ W1,     // [4,512]
                   const float* __restrict__ b1,     // [512]
                   const float* __restrict__ root1,  // [1,512]
                   const float* __restrict__ bias1,  // [512]
                   float* __restrict__ h1)           // [35,512]
{
    const int d = blockIdx.x;
    const int o = threadIdx.x;
    const float w0 = W1[o], w1 = W1[512 + o], w2 = W1[1024 + o], w3 = W1[1536 + o];
    const float bb = b1[o];
    float sum = 0.f;
#pragma unroll
    for (int s = 0; s < NN; ++s) {
        if (s == d) continue;
        const float4 a = ((const float4*)ea)[in_edge(s, d)];
        float w = fmaf(a.x, w0, fmaf(a.y, w1, fmaf(a.z, w2, fmaf(a.w, w3, bb))));
        sum = fmaf(x[s], fmaxf(w, 0.f), sum);
    }
    h1[d * 512 + o] = fmaxf(sum / 34.f + x[d] * root1[o] + bias1[o], 0.f);
}

// ---------------- Edge message kernel (layers 2,3) ----------------
// grid (NN srcs, NCH i-chunks), block O*EH threads (EH edge-halves of 17).
// partial[(c*NE + e)*O + o] = sum_{i in chunk c} h[s,i] * relu(a_e . W[:,i,o] + b[i,o])
template<int I, int O, int IC, int EH>
__global__ __launch_bounds__(O * EH)
void edge_msg(const float* __restrict__ h,     // [35, I]
              const float* __restrict__ ea,    // [1190,4]
              const float* __restrict__ W,     // [4, I*O]
              const float* __restrict__ bias,  // [I*O]
              float* __restrict__ partial)
{
    constexpr int TE = 34 / EH;
    const int s  = blockIdx.x;
    const int c  = blockIdx.y;
    const int i0 = c * IC;
    const int tid = threadIdx.x;
    const int o  = tid % O;
    const int eh = tid / O;

    // per-thread copy of this half's edge-attr vectors (block-uniform -> scalar regs)
    float4 a_r[TE];
#pragma unroll
    for (int t = 0; t < TE; ++t)
        a_r[t] = ((const float4*)ea)[s * 34 + eh * TE + t];

    float acc[TE];
#pragma unroll
    for (int t = 0; t < TE; ++t) acc[t] = 0.f;

    const float* __restrict__ hrow = h + (size_t)s * I + i0;

#pragma unroll 2
    for (int i = 0; i < IC; ++i) {
        const size_t base = (size_t)(i0 + i) * O + o;
        const float w0 = W[0 * (size_t)I * O + base];
        const float w1 = W[1 * (size_t)I * O + base];
        const float w2 = W[2 * (size_t)I * O + base];
        const float w3 = W[3 * (size_t)I * O + base];
        const float bb = bias[base];
        const float hv = hrow[i];   // block-uniform
#pragma unroll
        for (int t = 0; t < TE; ++t) {
            const float4 a = a_r[t];
            float w = fmaf(a.x, w0, fmaf(a.y, w1, fmaf(a.z, w2, fmaf(a.w, w3, bb))));
            acc[t] = fmaf(hv, fmaxf(w, 0.f), acc[t]);
        }
    }
#pragma unroll
    for (int t = 0; t < TE; ++t) {
        const int e = s * 34 + eh * TE + t;
        partial[((size_t)c * NE + e) * O + o] = acc[t];
    }
}

// ---------------- Node reduce (layers 2,3) ----------------
// hout[d,o] = relu( mean_e partial_sum + sum_i hprev[d,i]*root[i,o] + bias[o] )
template<int I, int O, int NCH>
__global__ __launch_bounds__(O)
void node_reduce(const float* __restrict__ partial,  // [NCH, NE, O]
                 const float* __restrict__ hprev,    // [35, I]
                 const float* __restrict__ root,     // [I, O]
                 const float* __restrict__ bias,     // [O]
                 float* __restrict__ hout)           // [35, O]
{
    const int d = blockIdx.x;
    const int o = threadIdx.x;
    float sum = 0.f;
    for (int c = 0; c < NCH; ++c) {
        const float* __restrict__ pc = partial + (size_t)c * NE * O;
#pragma unroll
        for (int s = 0; s < NN; ++s) {
            if (s == d) continue;
            sum += pc[(size_t)in_edge(s, d) * O + o];
        }
    }
    float r = 0.f;
#pragma unroll 8
    for (int i = 0; i < I; ++i)
        r = fmaf(hprev[(size_t)d * I + i], root[(size_t)i * O + o], r);
    hout[(size_t)d * O + o] = fmaxf(sum / 34.f + r + bias[o], 0.f);
}

// ---------------- Pairwise L1 ----------------
__global__ void cbt_kernel(const float* __restrict__ h,   // [35,128]
                           float* __restrict__ out)       // [35,35]
{
    const int idx = blockIdx.x * blockDim.x + threadIdx.x;
    if (idx >= NN * NN) return;
    const int a = idx / NN;
    const int i = idx % NN;
    float sum = 0.f;
#pragma unroll 8
    for (int f = 0; f < 128; ++f)
        sum += fabsf(h[i * 128 + f] - h[a * 128 + f]);
    out[idx] = sum;
}

extern "C" void kernel_launch(void* const* d_in, const int* in_sizes, int n_in,
                              void* d_out, int out_size, void* d_ws, size_t ws_size,
                              hipStream_t stream) {
    const float* x       = (const float*)d_in[0];
    const float* ea      = (const float*)d_in[1];
    const float* mlp1_w  = (const float*)d_in[3];
    const float* mlp1_b  = (const float*)d_in[4];
    const float* root1   = (const float*)d_in[5];
    const float* bias1   = (const float*)d_in[6];
    const float* mlp2_w  = (const float*)d_in[7];
    const float* mlp2_b  = (const float*)d_in[8];
    const float* root2   = (const float*)d_in[9];
    const float* bias2   = (const float*)d_in[10];
    const float* mlp3_w  = (const float*)d_in[11];
    const float* mlp3_b  = (const float*)d_in[12];
    const float* root3   = (const float*)d_in[13];
    const float* bias3   = (const float*)d_in[14];
    float* out = (float*)d_out;

    // workspace: partial buffer (reused by layers 2 & 3), then h1/h2/h3
    float* ws      = (float*)d_ws;
    float* partial = ws;                                   // max 8*1190*256 = 2,437,120 floats
    float* h1      = partial + (size_t)8 * NE * 256;       // 35*512
    float* h2      = h1 + 35 * 512;                        // 35*256
    float* h3      = h2 + 35 * 256;                        // 35*128

    // layer 1: 1 -> 512 (fused)
    layer1_kernel<<<NN, 512, 0, stream>>>(x, ea, mlp1_w, mlp1_b, root1, bias1, h1);

    // layer 2: 512 -> 256
    edge_msg<512, 256, 64, 2><<<dim3(NN, 8), 512, 0, stream>>>(h1, ea, mlp2_w, mlp2_b, partial);
    node_reduce<512, 256, 8><<<NN, 256, 0, stream>>>(partial, h1, root2, bias2, h2);

    // layer 3: 256 -> 128
    edge_msg<256, 128, 32, 2><<<dim3(NN, 8), 256, 0, stream>>>(h2, ea, mlp3_w, mlp3_b, partial);
    node_reduce<256, 128, 8><<<NN, 128, 0, stream>>>(partial, h2, root3, bias3, h3);

    // pairwise L1
    cbt_kernel<<<(NN * NN + 255) / 256, 256, 0, stream>>>(h3, out);
}

// Round 3
// 186.604 us; speedup vs baseline: 1.7529x; 1.7529x over previous
//
#include <hip/hip_runtime.h>

#define NN 35
#define NE 1190   // 35*34, src-major: edges of src s are e in [s*34, s*34+34)

// ---------------- Layer 1 (I=1) fused: h1[d,o] directly ----------------
__global__ __launch_bounds__(512)
void layer1_kernel(const float* __restrict__ x,      // [35,1]
                   const float* __restrict__ ea,     // [1190,4]
                   const float* __restrict__ W1,     // [4,512]
                   const float* __restrict__ b1,     // [512]
                   const float* __restrict__ root1,  // [1,512]
                   const float* __restrict__ bias1,  // [512]
                   float* __restrict__ h1)           // [35,512]
{
    const int d = blockIdx.x;
    const int o = threadIdx.x;
    const float w0 = W1[o], w1 = W1[512 + o], w2 = W1[1024 + o], w3 = W1[1536 + o];
    const float bb = b1[o];
    float sum = 0.f;
#pragma unroll
    for (int s = 0; s < NN; ++s) {
        if (s == d) continue;
        const int e = s * 34 + (d < s ? d : d - 1);
        const float4 a = ((const float4*)ea)[e];
        float w = fmaf(a.x, w0, fmaf(a.y, w1, fmaf(a.z, w2, fmaf(a.w, w3, bb))));
        sum = fmaf(x[s], fmaxf(w, 0.f), sum);
    }
    h1[d * 512 + o] = fmaxf(sum / 34.f + x[d] * root1[o] + bias1[o], 0.f);
}

// ---------------- Edge message + scatter (layers 2,3) ----------------
// grid (NN srcs, NCH i-chunks), block O*EH threads.
// atomically: agg[d,o] += (1/34) * sum_{i in chunk} h[s,i]*relu(a_e . W[:,i,o] + b[i,o])
// and (eh==0): agg[s,o] += sum_{i in chunk} h[s,i]*root[i,o]
template<int I, int O, int IC, int EH>
__global__ __launch_bounds__(O * EH)
void edge_msg_acc(const float* __restrict__ h,     // [35, I]
                  const float* __restrict__ ea,    // [1190,4]
                  const float* __restrict__ W,     // [4, I*O]
                  const float* __restrict__ bias,  // [I*O]
                  const float* __restrict__ root,  // [I, O]
                  float* __restrict__ agg)         // [35, O]
{
    constexpr int TE = 34 / EH;
    const int s   = blockIdx.x;
    const int c   = blockIdx.y;
    const int i0  = c * IC;
    const int tid = threadIdx.x;
    const int o   = tid % O;
    const int eh  = tid / O;

    __shared__ float4 as[34];
    if (tid < 34) as[tid] = ((const float4*)ea)[s * 34 + tid];
    __syncthreads();

    float acc[TE];
#pragma unroll
    for (int t = 0; t < TE; ++t) acc[t] = 0.f;

    const float* __restrict__ hrow = h + (size_t)s * I + i0;

#pragma unroll 2
    for (int i = 0; i < IC; ++i) {
        const size_t base = (size_t)(i0 + i) * O + o;
        const float w0 = W[0 * (size_t)I * O + base];
        const float w1 = W[1 * (size_t)I * O + base];
        const float w2 = W[2 * (size_t)I * O + base];
        const float w3 = W[3 * (size_t)I * O + base];
        const float bb = bias[base];
        const float hv = hrow[i];   // block-uniform
#pragma unroll
        for (int t = 0; t < TE; ++t) {
            const float4 a = as[eh * TE + t];   // wave-uniform -> LDS broadcast
            float w = fmaf(a.x, w0, fmaf(a.y, w1, fmaf(a.z, w2, fmaf(a.w, w3, bb))));
            acc[t] = fmaf(hv, fmaxf(w, 0.f), acc[t]);
        }
    }

    // scatter messages (mean pre-scaled)
#pragma unroll
    for (int t = 0; t < TE; ++t) {
        const int j = eh * TE + t;            // position in s's dst list
        const int d = (j < s) ? j : j + 1;
        atomicAdd(&agg[d * O + o], acc[t] * (1.f / 34.f));
    }

    // fused root-matvec partial for node s (wave-uniform branch)
    if (eh == 0) {
        float r = 0.f;
#pragma unroll 4
        for (int i = 0; i < IC; ++i)
            r = fmaf(hrow[i], root[(size_t)(i0 + i) * O + o], r);
        atomicAdd(&agg[s * O + o], r);
    }
}

// ---------------- Activation: h = relu(agg + bias) ----------------
template<int O>
__global__ __launch_bounds__(O)
void act_kernel(const float* __restrict__ agg, const float* __restrict__ bias,
                float* __restrict__ hout)
{
    const int d = blockIdx.x;
    const int o = threadIdx.x;
    hout[d * O + o] = fmaxf(agg[d * O + o] + bias[o], 0.f);
}

// ---------------- Pairwise L1 ----------------
__global__ void cbt_kernel(const float* __restrict__ h,   // [35,128]
                           float* __restrict__ out)       // [35,35]
{
    const int idx = blockIdx.x * blockDim.x + threadIdx.x;
    if (idx >= NN * NN) return;
    const int a = idx / NN;
    const int i = idx % NN;
    float sum = 0.f;
#pragma unroll 8
    for (int f = 0; f < 128; ++f)
        sum += fabsf(h[i * 128 + f] - h[a * 128 + f]);
    out[idx] = sum;
}

extern "C" void kernel_launch(void* const* d_in, const int* in_sizes, int n_in,
                              void* d_out, int out_size, void* d_ws, size_t ws_size,
                              hipStream_t stream) {
    const float* x       = (const float*)d_in[0];
    const float* ea      = (const float*)d_in[1];
    const float* mlp1_w  = (const float*)d_in[3];
    const float* mlp1_b  = (const float*)d_in[4];
    const float* root1   = (const float*)d_in[5];
    const float* bias1   = (const float*)d_in[6];
    const float* mlp2_w  = (const float*)d_in[7];
    const float* mlp2_b  = (const float*)d_in[8];
    const float* root2   = (const float*)d_in[9];
    const float* bias2   = (const float*)d_in[10];
    const float* mlp3_w  = (const float*)d_in[11];
    const float* mlp3_b  = (const float*)d_in[12];
    const float* root3   = (const float*)d_in[13];
    const float* bias3   = (const float*)d_in[14];
    float* out = (float*)d_out;

    // workspace layout (floats): agg2, agg3 contiguous (one memset), then h1..h3
    float* ws   = (float*)d_ws;
    float* agg2 = ws;                  // 35*256 = 8960
    float* agg3 = agg2 + 35 * 256;     // 35*128 = 4480
    float* h1   = agg3 + 35 * 128;     // 35*512
    float* h2   = h1 + 35 * 512;       // 35*256
    float* h3   = h2 + 35 * 256;       // 35*128

    hipMemsetAsync(ws, 0, (size_t)(35 * 256 + 35 * 128) * sizeof(float), stream);

    // layer 1: 1 -> 512 (fused)
    layer1_kernel<<<NN, 512, 0, stream>>>(x, ea, mlp1_w, mlp1_b, root1, bias1, h1);

    // layer 2: 512 -> 256
    edge_msg_acc<512, 256, 64, 2><<<dim3(NN, 8), 512, 0, stream>>>(h1, ea, mlp2_w, mlp2_b, root2, agg2);
    act_kernel<256><<<NN, 256, 0, stream>>>(agg2, bias2, h2);

    // layer 3: 256 -> 128
    edge_msg_acc<256, 128, 32, 2><<<dim3(NN, 8), 256, 0, stream>>>(h2, ea, mlp3_w, mlp3_b, root3, agg3);
    act_kernel<128><<<NN, 128, 0, stream>>>(agg3, bias3, h3);

    // pairwise L1
    cbt_kernel<<<(NN * NN + 255) / 256, 256, 0, stream>>>(h3, out);
}

// Round 4
// 141.862 us; speedup vs baseline: 2.3057x; 1.3154x over previous
//
#include <hip/hip_runtime.h>

#define NN 35
#define NE 1190   // 35*34, src-major: edges of src s are e in [s*34, s*34+34)

// ---------------- Layer 1 (I=1) fused: h1[d,o] directly ----------------
__global__ __launch_bounds__(512)
void layer1_kernel(const float* __restrict__ x,      // [35,1]
                   const float* __restrict__ ea,     // [1190,4]
                   const float* __restrict__ W1,     // [4,512]
                   const float* __restrict__ b1,     // [512]
                   const float* __restrict__ root1,  // [1,512]
                   const float* __restrict__ bias1,  // [512]
                   float* __restrict__ h1)           // [35,512]
{
    const int d = blockIdx.x;
    const int o = threadIdx.x;
    const float w0 = W1[o], w1 = W1[512 + o], w2 = W1[1024 + o], w3 = W1[1536 + o];
    const float bb = b1[o];
    float sum = 0.f;
#pragma unroll
    for (int s = 0; s < NN; ++s) {
        if (s == d) continue;
        const int e = s * 34 + (d < s ? d : d - 1);
        const float4 a = ((const float4*)ea)[e];
        float w = fmaf(a.x, w0, fmaf(a.y, w1, fmaf(a.z, w2, fmaf(a.w, w3, bb))));
        sum = fmaf(x[s], fmaxf(w, 0.f), sum);
    }
    h1[d * 512 + o] = fmaxf(sum / 34.f + x[d] * root1[o] + bias1[o], 0.f);
}

// ---------------- Dst-major edge kernel (layers 2,3) ----------------
// Block (d, c): accumulate over all 34 incoming edges for i-chunk c, plus
// the root-matvec contribution of d's own row. ONE atomic per thread.
// agg[d,o] += (1/34)*sum_j sum_{i in c} h[s_j,i]*relu(a_j . W[:,i,o]+b[i,o])
//           + sum_{i in c} h[d,i]*root[i,o]
template<int I, int O, int IC>
__global__ __launch_bounds__(O)
void edge_msg_acc(const float* __restrict__ h,     // [35, I]
                  const float* __restrict__ ea,    // [1190,4]
                  const float* __restrict__ W,     // [4, I*O]
                  const float* __restrict__ bias,  // [I*O]
                  const float* __restrict__ root,  // [I, O]
                  float* __restrict__ agg)         // [35, O]
{
    constexpr int K4 = IC / 4;
    const int d  = blockIdx.x;
    const int c  = blockIdx.y;
    const int i0 = c * IC;
    const int o  = threadIdx.x;

    __shared__ __align__(16) float hs[35][IC];  // rows 0..33: sources, row 34: d
    __shared__ float4 as[34];

    if (o < 35) {
        const int s = (o < 34) ? (o + (o >= d ? 1 : 0)) : d;
        const float4* hp = (const float4*)(h + (size_t)s * I + i0);
#pragma unroll
        for (int k = 0; k < K4; ++k) ((float4*)hs[o])[k] = hp[k];
    }
    if (o >= 64 && o < 98) {
        const int j = o - 64;
        const int s = j + (j >= d ? 1 : 0);
        as[j] = ((const float4*)ea)[s * 34 + (d < s ? d : d - 1)];
    }
    __syncthreads();

    // preload W chunk + bias + root column into registers
    float w0[IC], w1[IC], w2[IC], w3[IC], bb[IC], rr[IC];
#pragma unroll
    for (int i = 0; i < IC; ++i) {
        const size_t base = (size_t)(i0 + i) * O + o;
        w0[i] = W[0 * (size_t)I * O + base];
        w1[i] = W[1 * (size_t)I * O + base];
        w2[i] = W[2 * (size_t)I * O + base];
        w3[i] = W[3 * (size_t)I * O + base];
        bb[i] = bias[base];
        rr[i] = root[base];
    }

    float acc = 0.f;
#pragma unroll 2
    for (int j = 0; j < 34; ++j) {
        const float4 a = as[j];
#pragma unroll
        for (int k = 0; k < K4; ++k) {
            const float4 hv = ((const float4*)hs[j])[k];
            const float hm[4] = {hv.x, hv.y, hv.z, hv.w};
#pragma unroll
            for (int m = 0; m < 4; ++m) {
                const int i = k * 4 + m;
                float w = fmaf(a.x, w0[i], fmaf(a.y, w1[i],
                          fmaf(a.z, w2[i], fmaf(a.w, w3[i], bb[i]))));
                acc = fmaf(hm[m], fmaxf(w, 0.f), acc);
            }
        }
    }

    // root contribution from d's own row (slot 34)
    float racc = 0.f;
#pragma unroll
    for (int k = 0; k < K4; ++k) {
        const float4 hv = ((const float4*)hs[34])[k];
        const float hm[4] = {hv.x, hv.y, hv.z, hv.w};
#pragma unroll
        for (int m = 0; m < 4; ++m) racc = fmaf(hm[m], rr[k * 4 + m], racc);
    }

    atomicAdd(&agg[d * O + o], acc * (1.f / 34.f) + racc);
}

// ---------------- Activation: h = relu(agg + bias) ----------------
template<int O>
__global__ __launch_bounds__(O)
void act_kernel(const float* __restrict__ agg, const float* __restrict__ bias,
                float* __restrict__ hout)
{
    const int d = blockIdx.x;
    const int o = threadIdx.x;
    hout[d * O + o] = fmaxf(agg[d * O + o] + bias[o], 0.f);
}

// ---------------- Pairwise L1 ----------------
__global__ void cbt_kernel(const float* __restrict__ h,   // [35,128]
                           float* __restrict__ out)       // [35,35]
{
    const int idx = blockIdx.x * blockDim.x + threadIdx.x;
    if (idx >= NN * NN) return;
    const int a = idx / NN;
    const int i = idx % NN;
    float sum = 0.f;
#pragma unroll 8
    for (int f = 0; f < 128; ++f)
        sum += fabsf(h[i * 128 + f] - h[a * 128 + f]);
    out[idx] = sum;
}

extern "C" void kernel_launch(void* const* d_in, const int* in_sizes, int n_in,
                              void* d_out, int out_size, void* d_ws, size_t ws_size,
                              hipStream_t stream) {
    const float* x       = (const float*)d_in[0];
    const float* ea      = (const float*)d_in[1];
    const float* mlp1_w  = (const float*)d_in[3];
    const float* mlp1_b  = (const float*)d_in[4];
    const float* root1   = (const float*)d_in[5];
    const float* bias1   = (const float*)d_in[6];
    const float* mlp2_w  = (const float*)d_in[7];
    const float* mlp2_b  = (const float*)d_in[8];
    const float* root2   = (const float*)d_in[9];
    const float* bias2   = (const float*)d_in[10];
    const float* mlp3_w  = (const float*)d_in[11];
    const float* mlp3_b  = (const float*)d_in[12];
    const float* root3   = (const float*)d_in[13];
    const float* bias3   = (const float*)d_in[14];
    float* out = (float*)d_out;

    // workspace layout (floats): agg2, agg3 contiguous (one memset), then h1..h3
    float* ws   = (float*)d_ws;
    float* agg2 = ws;                  // 35*256
    float* agg3 = agg2 + 35 * 256;     // 35*128
    float* h1   = agg3 + 35 * 128;     // 35*512
    float* h2   = h1 + 35 * 512;       // 35*256
    float* h3   = h2 + 35 * 256;       // 35*128

    hipMemsetAsync(ws, 0, (size_t)(35 * 256 + 35 * 128) * sizeof(float), stream);

    // layer 1: 1 -> 512 (fused)
    layer1_kernel<<<NN, 512, 0, stream>>>(x, ea, mlp1_w, mlp1_b, root1, bias1, h1);

    // layer 2: 512 -> 256, IC=16 -> 32 chunks
    edge_msg_acc<512, 256, 16><<<dim3(NN, 32), 256, 0, stream>>>(h1, ea, mlp2_w, mlp2_b, root2, agg2);
    act_kernel<256><<<NN, 256, 0, stream>>>(agg2, bias2, h2);

    // layer 3: 256 -> 128, IC=8 -> 32 chunks
    edge_msg_acc<256, 128, 8><<<dim3(NN, 32), 128, 0, stream>>>(h2, ea, mlp3_w, mlp3_b, root3, agg3);
    act_kernel<128><<<NN, 128, 0, stream>>>(agg3, bias3, h3);

    // pairwise L1
    cbt_kernel<<<(NN * NN + 255) / 256, 256, 0, stream>>>(h3, out);
}